// Round 4
// baseline (261.309 us; speedup 1.0000x reference)
//
#include <hip/hip_runtime.h>
#include <stdint.h>

typedef unsigned short u16;
typedef __attribute__((ext_vector_type(8))) short short8;   // 8 bf16 MFMA operand
typedef __attribute__((ext_vector_type(4))) short short4v;
typedef __attribute__((ext_vector_type(4))) float f4;
typedef __attribute__((ext_vector_type(4))) float f32x4;

static __device__ __forceinline__ u16 f2b(float f) {
  union { float f; uint32_t u; } c; c.f = f;
  return (u16)((c.u + 0x7FFFu + ((c.u >> 16) & 1u)) >> 16);   // RNE
}
static __device__ __forceinline__ float b2f(u16 s) {
  union { uint32_t u; float f; } c; c.u = ((uint32_t)s) << 16; return c.f;
}

// ---------------- prep: x,h (f32) -> bf16 Ab[65536][512] ----------------
__global__ __launch_bounds__(256) void cvt_kernel(const float* __restrict__ x,
                                                  const float* __restrict__ h,
                                                  u16* __restrict__ Ab) {
  const size_t half = (size_t)32768 * 512;
  size_t tid = (size_t)blockIdx.x * blockDim.x + threadIdx.x;
  size_t nth = (size_t)gridDim.x * blockDim.x;
  size_t total8 = (half * 2) >> 3;
  for (size_t t = tid; t < total8; t += nth) {
    size_t e = t << 3;
    const float* src = (e < half) ? (x + e) : (h + (e - half));
    f4 v0 = *(const f4*)src;
    f4 v1 = *(const f4*)(src + 4);
    short8 o;
    o[0] = (short)f2b(v0[0]); o[1] = (short)f2b(v0[1]);
    o[2] = (short)f2b(v0[2]); o[3] = (short)f2b(v0[3]);
    o[4] = (short)f2b(v1[0]); o[5] = (short)f2b(v1[1]);
    o[6] = (short)f2b(v1[2]); o[7] = (short)f2b(v1[3]);
    *(short8*)(Ab + e) = o;
  }
}

// ---- prep: WT[n][k] = concat_n(srcA (512 x NA), srcB (512 x NB)) transposed, bf16
__global__ __launch_bounds__(256) void transpose_cat(const float* __restrict__ srcA,
                                                     const float* __restrict__ srcB,
                                                     u16* __restrict__ dst,
                                                     int NA, int NB) {
  __shared__ float t[32][33];
  int n0 = blockIdx.x * 32, k0 = blockIdx.y * 32;
  int tx = threadIdx.x, ty = threadIdx.y;
  const float* src; int strideN, nb;
  if (n0 < NA) { src = srcA; strideN = NA; nb = n0; }
  else         { src = srcB; strideN = NB; nb = n0 - NA; }
#pragma unroll
  for (int i = 0; i < 4; ++i) {
    int k = k0 + ty + i * 8;
    t[tx][ty + i * 8] = src[(size_t)k * strideN + nb + tx];
  }
  __syncthreads();
#pragma unroll
  for (int i = 0; i < 4; ++i) {
    int n = ty + i * 8;
    dst[(size_t)(n0 + n) * 512 + k0 + tx] = f2b(t[n][tx]);
  }
}

// ---------------- GEMM: Cb[m][n] = sum_k Ab[m][k] * WT[n][k] ----------------
// Persistent blocks: 256x128 tile, BK=64, 8 waves (4M x 2N), 16x16x32 MFMA,
// 3-stage LDS ring (3 x 48 KB), continuous K-pipeline across output tiles,
// counted vmcnt (6 normal / 22 after stores / 0 only at pipeline tail).
// Proven BK=64 involution swizzle (rounds 1/3: 0 bank conflicts).
#define AS1 __attribute__((address_space(1)))
#define AS3 __attribute__((address_space(3)))
#define SBAR0 __builtin_amdgcn_sched_barrier(0)

__global__ __launch_bounds__(512, 1) void gemm_kernel(
    const u16* __restrict__ Ab, const u16* __restrict__ WxT,
    const u16* __restrict__ WhT, u16* __restrict__ Cb,
    int rowStartX, int rowStartH, int tphm, int KOT) {
  __shared__ u16 lds[3 * 24576];   // ring buf q at q*24576: A[256][64] @ +0, B[128][64] @ +16384

  int tid = threadIdx.x, lane = tid & 63, wv = tid >> 6;
  int wm = wv >> 1, wn = wv & 1;          // 4M x 2N wave grid
  int l15 = lane & 15, l4 = lane >> 4;

  int nwg = gridDim.x, bid = blockIdx.x;
  int swz = (nwg & 7) ? bid : ((bid & 7) * (nwg >> 3) + (bid >> 3));

  // staging thread-constants: slot = row*8 + sl; stored sl holds k-chunk sl^(row&7)
  int stRow = tid >> 3;                    // 0..63 (row within 64-row issue group)
  int g8 = ((tid & 7) ^ (stRow & 7)) * 8;  // pre-swizzled source k-offset (u16)
  int dOff = tid * 8;                      // dst u16 offset within issue group

  // staging pointers for the output-tile currently being staged
  const u16 *pA0, *pA1, *pA2, *pA3, *pB0, *pB1;
#define SETSTAGE(o) do { \
    int _ot = swz * KOT + (o); \
    int _mb = _ot / 12, _nb = _ot - _mb * 12; \
    size_t _am0 = (_mb < tphm) ? (size_t)rowStartX + (size_t)_mb * 256 \
                               : (size_t)rowStartH + (size_t)(_mb - tphm) * 256; \
    const u16* _Wt = (_mb < tphm) ? WxT : WhT; \
    pA0 = Ab + (_am0 +   0 + stRow) * 512 + g8; \
    pA1 = Ab + (_am0 +  64 + stRow) * 512 + g8; \
    pA2 = Ab + (_am0 + 128 + stRow) * 512 + g8; \
    pA3 = Ab + (_am0 + 192 + stRow) * 512 + g8; \
    pB0 = _Wt + ((size_t)_nb * 128 +  0 + stRow) * 512 + g8; \
    pB1 = _Wt + ((size_t)_nb * 128 + 64 + stRow) * 512 + g8; \
  } while (0)

#define STG(kt, bufq) do { \
    u16* _b = lds + (bufq) * 24576; \
    int _ko = (kt) << 6; \
    __builtin_amdgcn_global_load_lds((const AS1 void*)(pA0 + _ko), (AS3 void*)(_b +  0    + dOff), 16, 0, 0); \
    __builtin_amdgcn_global_load_lds((const AS1 void*)(pA1 + _ko), (AS3 void*)(_b + 4096  + dOff), 16, 0, 0); \
    __builtin_amdgcn_global_load_lds((const AS1 void*)(pA2 + _ko), (AS3 void*)(_b + 8192  + dOff), 16, 0, 0); \
    __builtin_amdgcn_global_load_lds((const AS1 void*)(pA3 + _ko), (AS3 void*)(_b + 12288 + dOff), 16, 0, 0); \
    __builtin_amdgcn_global_load_lds((const AS1 void*)(pB0 + _ko), (AS3 void*)(_b + 16384 + dOff), 16, 0, 0); \
    __builtin_amdgcn_global_load_lds((const AS1 void*)(pB1 + _ko), (AS3 void*)(_b + 20480 + dOff), 16, 0, 0); \
  } while (0)

  // fragment read offsets (u16): row*64 + slot*8, slot = kc ^ (row&7)
  int sl0 = (l4 ^ (l15 & 7)) * 8;           // ks=0 (kc = l4)
  int sl1 = ((4 + l4) ^ (l15 & 7)) * 8;     // ks=1 (kc = 4+l4)
  int aOff = (wm * 64 + l15) * 64;          // + mr*1024
  int bOff = 16384 + (wn * 64 + l15) * 64;  // + nr*1024

  f32x4 acc[4][4] = {};

  SETSTAGE(0);
  STG(0, 0); STG(1, 1);
  asm volatile("s_waitcnt vmcnt(6)" ::: "memory");   // tile 0 resident, tile 1 in flight
  SBAR0; __builtin_amdgcn_s_barrier(); SBAR0;

  int T = KOT * 8;
  int bufC = 0;
  for (int j = 0; j < T; ++j) {
    u16* buf = lds + bufC * 24576;
    int j2 = j + 2;
    if (j2 < T) {
      int kt2 = j2 & 7;
      if (kt2 == 0) SETSTAGE(j2 >> 3);
      int bufS = bufC - 1; if (bufS < 0) bufS = 2;   // (bufC+2)%3
      STG(kt2, bufS);
    }
    short8 afr[4], bfr[4];
    // ---- phase 0: ks=0
#pragma unroll
    for (int nr = 0; nr < 4; ++nr) bfr[nr] = *(const short8*)(buf + bOff + nr * 1024 + sl0);
#pragma unroll
    for (int mr = 0; mr < 4; ++mr) afr[mr] = *(const short8*)(buf + aOff + mr * 1024 + sl0);
    SBAR0; __builtin_amdgcn_s_barrier(); SBAR0;
    __builtin_amdgcn_s_setprio(1);
#pragma unroll
    for (int mr = 0; mr < 4; ++mr)
#pragma unroll
      for (int nr = 0; nr < 4; ++nr)
        acc[mr][nr] = __builtin_amdgcn_mfma_f32_16x16x32_bf16(bfr[nr], afr[mr], acc[mr][nr], 0, 0, 0);
    __builtin_amdgcn_s_setprio(0);
    // ---- phase 1: ks=1
#pragma unroll
    for (int nr = 0; nr < 4; ++nr) bfr[nr] = *(const short8*)(buf + bOff + nr * 1024 + sl1);
#pragma unroll
    for (int mr = 0; mr < 4; ++mr) afr[mr] = *(const short8*)(buf + aOff + mr * 1024 + sl1);
    SBAR0; __builtin_amdgcn_s_barrier(); SBAR0;
    __builtin_amdgcn_s_setprio(1);
#pragma unroll
    for (int mr = 0; mr < 4; ++mr)
#pragma unroll
      for (int nr = 0; nr < 4; ++nr)
        acc[mr][nr] = __builtin_amdgcn_mfma_f32_16x16x32_bf16(bfr[nr], afr[mr], acc[mr][nr], 0, 0, 0);
    __builtin_amdgcn_s_setprio(0);
    // ---- output-tile end: store + reset acc (stores overlap next tile's pipeline)
    if ((j & 7) == 7) {
      int ot = swz * KOT + (j >> 3);
      int mb = ot / 12, nb = ot - mb * 12;
      int crow0 = mb * 256, n0 = nb * 128;
#pragma unroll
      for (int mr = 0; mr < 4; ++mr) {
        int m = crow0 + wm * 64 + mr * 16 + l15;
#pragma unroll
        for (int nr = 0; nr < 4; ++nr) {
          int n = n0 + wn * 64 + nr * 16 + l4 * 4;
          short4v o;
          o[0] = (short)f2b(acc[mr][nr][0]);
          o[1] = (short)f2b(acc[mr][nr][1]);
          o[2] = (short)f2b(acc[mr][nr][2]);
          o[3] = (short)f2b(acc[mr][nr][3]);
          *(short4v*)(Cb + (size_t)m * 1536 + n) = o;
          acc[mr][nr] = (f32x4)(0.0f);
        }
      }
    }
    // ---- iteration boundary: counted drain (tile j+1 must be resident)
    if (j < T - 1) {
      if (j2 < T) {
        if ((j & 7) == 7) { asm volatile("s_waitcnt vmcnt(22)" ::: "memory"); }
        else             { asm volatile("s_waitcnt vmcnt(6)"  ::: "memory"); }
      } else             { asm volatile("s_waitcnt vmcnt(0)"  ::: "memory"); }
      SBAR0; __builtin_amdgcn_s_barrier(); SBAR0;
    }
    bufC++; if (bufC == 3) bufC = 0;
  }
#undef STG
#undef SETSTAGE
}

// ---------------- epilogue: bias + 4x LN + gates + output ----------------
__global__ __launch_bounds__(256) void epi_kernel(
    const u16* __restrict__ Cb, const float* __restrict__ h,
    const float* __restrict__ b_i2h, const float* __restrict__ b_h2h,
    const float* __restrict__ b_hatW, const float* __restrict__ b_hatU,
    float* __restrict__ out, int mBase, int BC) {
  int wv = threadIdx.x >> 6;
  int lane = threadIdx.x & 63;
  int mLocal = blockIdx.x * 4 + wv;
  size_t mGlob = (size_t)mBase + mLocal;
  const u16* Ar = Cb + (size_t)mLocal * 1536;
  const u16* Br = Cb + ((size_t)BC + mLocal) * 1536;
  int j0 = lane * 8;

  float a[3][8], b[3][8];
#pragma unroll
  for (int c = 0; c < 3; ++c) {
    short8 va = *(const short8*)(Ar + c * 512 + j0);
    short8 vb = *(const short8*)(Br + c * 512 + j0);
    const float* biasA = (c == 0) ? (b_i2h + j0) : (c == 1) ? (b_i2h + 512 + j0) : (b_hatW + j0);
    const float* biasB = (c == 0) ? (b_h2h + j0) : (c == 1) ? (b_h2h + 512 + j0) : (b_hatU + j0);
    f4 ba0 = *(const f4*)biasA, ba1 = *(const f4*)(biasA + 4);
    f4 bb0 = *(const f4*)biasB, bb1 = *(const f4*)(biasB + 4);
#pragma unroll
    for (int j = 0; j < 4; ++j) {
      a[c][j]     = b2f((u16)va[j])     + ba0[j];
      a[c][j + 4] = b2f((u16)va[j + 4]) + ba1[j];
      b[c][j]     = b2f((u16)vb[j])     + bb0[j];
      b[c][j + 4] = b2f((u16)vb[j + 4]) + bb1[j];
    }
  }

  float s1a = 0, q1a = 0, s2a = 0, q2a = 0, s1b = 0, q1b = 0, s2b = 0, q2b = 0;
#pragma unroll
  for (int j = 0; j < 8; ++j) {
    s1a += a[0][j] + a[1][j]; q1a += a[0][j] * a[0][j] + a[1][j] * a[1][j];
    s2a += a[2][j];           q2a += a[2][j] * a[2][j];
    s1b += b[0][j] + b[1][j]; q1b += b[0][j] * b[0][j] + b[1][j] * b[1][j];
    s2b += b[2][j];           q2b += b[2][j] * b[2][j];
  }
#pragma unroll
  for (int off = 32; off > 0; off >>= 1) {
    s1a += __shfl_xor(s1a, off); q1a += __shfl_xor(q1a, off);
    s2a += __shfl_xor(s2a, off); q2a += __shfl_xor(q2a, off);
    s1b += __shfl_xor(s1b, off); q1b += __shfl_xor(q1b, off);
    s2b += __shfl_xor(s2b, off); q2b += __shfl_xor(q2b, off);
  }
  const float inv1 = 1.0f / 1024.0f, inv2 = 1.0f / 512.0f, eps = 1e-5f;
  float mu1a = s1a * inv1, mu2a = s2a * inv2, mu1b = s1b * inv1, mu2b = s2b * inv2;
  float rs1a = rsqrtf(q1a * inv1 - mu1a * mu1a + eps);
  float rs2a = rsqrtf(q2a * inv2 - mu2a * mu2a + eps);
  float rs1b = rsqrtf(q1b * inv1 - mu1b * mu1b + eps);
  float rs2b = rsqrtf(q2b * inv2 - mu2b * mu2b + eps);

  const float* hrow = h + mGlob * 512 + j0;
  f4 h0 = *(const f4*)hrow, h1 = *(const f4*)(hrow + 4);
  f4 o0, o1;
#pragma unroll
  for (int j = 0; j < 8; ++j) {
    float zs  = (a[0][j] - mu1a) * rs1a + (b[0][j] - mu1b) * rs1b;
    float rsg = (a[1][j] - mu1a) * rs1a + (b[1][j] - mu1b) * rs1b;
    float z = 1.0f / (1.0f + __expf(-zs));
    float r = 1.0f / (1.0f + __expf(-rsg));
    float hh = tanhf((a[2][j] - mu2a) * rs2a + r * ((b[2][j] - mu2b) * rs2b));
    float hv = (j < 4) ? h0[j] : h1[j - 4];
    float o = hv + z * (hh - hv);
    if (j < 4) o0[j] = o; else o1[j - 4] = o;
  }
  *(f4*)(out + mGlob * 512 + j0) = o0;
  *(f4*)(out + mGlob * 512 + j0 + 4) = o1;
}

extern "C" void kernel_launch(void* const* d_in, const int* in_sizes, int n_in,
                              void* d_out, int out_size, void* d_ws, size_t ws_size,
                              hipStream_t stream) {
  const float* x      = (const float*)d_in[0];
  const float* h      = (const float*)d_in[1];
  const float* W_i2h  = (const float*)d_in[2];
  const float* b_i2h  = (const float*)d_in[3];
  const float* W_h2h  = (const float*)d_in[4];
  const float* b_h2h  = (const float*)d_in[5];
  const float* W_hatW = (const float*)d_in[6];
  const float* b_hatW = (const float*)d_in[7];
  const float* W_hatU = (const float*)d_in[8];
  const float* b_hatU = (const float*)d_in[9];
  float* out = (float*)d_out;

  u16* WxT = (u16*)d_ws;                       // [1536][512]
  u16* WhT = WxT + (size_t)1536 * 512;         // [1536][512]
  u16* Ab  = WhT + (size_t)1536 * 512;         // [65536][512] = bf16(x);bf16(h)
  u16* Cb  = Ab + (size_t)65536 * 512;         // [2*BC][1536] chunk buffer

  size_t fixedElems = (size_t)2 * 1536 * 512 + (size_t)65536 * 512;
  int chunks = 1;
  for (;;) {
    size_t need = (fixedElems + (size_t)2 * (32768 / chunks) * 1536) * sizeof(u16);
    if (need <= ws_size || chunks >= 128) break;
    chunks <<= 1;
  }
  int BC = 32768 / chunks;
  int tphm = BC / 256;             // m-tiles per half (256-row tiles)
  int totOt = 2 * tphm * 12;       // output tiles per dispatch (256x128 each)
  int nwg = 256;
  while (totOt % nwg) nwg >>= 1;
  int KOT = totOt / nwg;

  cvt_kernel<<<2048, 256, 0, stream>>>(x, h, Ab);
  transpose_cat<<<dim3(48, 16), dim3(32, 8), 0, stream>>>(W_i2h, W_hatW, WxT, 1024, 512);
  transpose_cat<<<dim3(48, 16), dim3(32, 8), 0, stream>>>(W_h2h, W_hatU, WhT, 1024, 512);
  for (int cc = 0; cc < chunks; ++cc) {
    gemm_kernel<<<nwg, 512, 0, stream>>>(Ab, WxT, WhT, Cb,
                                         cc * BC, 32768 + cc * BC, tphm, KOT);
    epi_kernel<<<BC / 4, 256, 0, stream>>>(Cb, h, b_i2h, b_h2h, b_hatW, b_hatU,
                                           out, cc * BC, BC);
  }
}